// Round 1
// baseline (6767.337 us; speedup 1.0000x reference)
//
#include <hip/hip_runtime.h>

// LightGCN propagation: out = 0.25*(e0 + S e0 + S^2 e0 + S^3 e0)
// Horner: t1 = S e0; t2 = S(e0+t1); t3 = S(e0+t1+t2)  [since t2 holds e1+e2]
//   X(=d_out) <- S e0                      = e1
//   Y(=d_ws)  <- S (e0 + X)                = e2 + e1's contribution... see below
//   X zeroed, X <- S (e0 + Y)
//   out = 0.25*(e0 + X)
// Verify: X1 = e1. Y = S(e0+e1) = e1+e2. X2 = S(e0+e1+e2) = e1+e2+e3.
// final = 0.25*(e0+e1+e2+e3). Correct.

#define NUSERS 100000
#define NITEMS 400000
#define NNODES 500000
#define EMB 64
#define NNZ_TOTAL 10000000

__global__ void spmm_atomic(const float* __restrict__ vals,
                            const int* __restrict__ rows,
                            const int* __restrict__ cols,
                            const float* __restrict__ user_emb,
                            const float* __restrict__ item_emb,
                            const float* __restrict__ prev,  // may be null
                            float* __restrict__ y) {
  const int lane = threadIdx.x & 63;
  int wave = (int)((blockIdx.x * blockDim.x + threadIdx.x) >> 6);
  const int nwaves = (int)((gridDim.x * blockDim.x) >> 6);
  for (int nz = wave; nz < NNZ_TOTAL; nz += nwaves) {
    float v = vals[nz];   // all 64 lanes same address -> broadcast
    int r = rows[nz];
    int c = cols[nz];
    // gather e0[c] straight from the input tables (wave-uniform branch)
    float xv = (c < NUSERS) ? user_emb[(size_t)c * EMB + lane]
                            : item_emb[(size_t)(c - NUSERS) * EMB + lane];
    if (prev) xv += prev[(size_t)c * EMB + lane];
    atomicAdd(&y[(size_t)r * EMB + lane], v * xv);
  }
}

__global__ void final_combine(const float* __restrict__ user_emb,
                              const float* __restrict__ item_emb,
                              float* __restrict__ out) {
  // out[i] = 0.25f*(e0[i] + out[i]), float4-vectorized
  const int n4 = NNODES * EMB / 4;
  const int u4 = NUSERS * EMB / 4;
  int i = blockIdx.x * blockDim.x + threadIdx.x;
  if (i >= n4) return;
  float4 a = (i < u4) ? ((const float4*)user_emb)[i]
                      : ((const float4*)item_emb)[i - u4];
  float4 b = ((const float4*)out)[i];
  float4 r;
  r.x = 0.25f * (a.x + b.x);
  r.y = 0.25f * (a.y + b.y);
  r.z = 0.25f * (a.z + b.z);
  r.w = 0.25f * (a.w + b.w);
  ((float4*)out)[i] = r;
}

extern "C" void kernel_launch(void* const* d_in, const int* in_sizes, int n_in,
                              void* d_out, int out_size, void* d_ws, size_t ws_size,
                              hipStream_t stream) {
  const float* user_emb = (const float*)d_in[0];
  const float* item_emb = (const float*)d_in[1];
  const float* vals     = (const float*)d_in[2];
  const int*   rows     = (const int*)d_in[3];
  const int*   cols     = (const int*)d_in[4];
  float* out = (float*)d_out;          // doubles as ping-pong buffer X
  float* Y   = (float*)d_ws;           // 128 MB scratch buffer

  const size_t bytes = (size_t)NNODES * EMB * sizeof(float);

  hipMemsetAsync(out, 0, bytes, stream);
  hipMemsetAsync(Y, 0, bytes, stream);

  dim3 blk(256);
  dim3 grid(4096);  // 16384 waves, grid-stride over 10M nnz

  // layer 1: X += S e0
  spmm_atomic<<<grid, blk, 0, stream>>>(vals, rows, cols, user_emb, item_emb,
                                        nullptr, out);
  // layer 2: Y += S (e0 + X)
  spmm_atomic<<<grid, blk, 0, stream>>>(vals, rows, cols, user_emb, item_emb,
                                        out, Y);
  // layer 3: X <- 0; X += S (e0 + Y)
  hipMemsetAsync(out, 0, bytes, stream);
  spmm_atomic<<<grid, blk, 0, stream>>>(vals, rows, cols, user_emb, item_emb,
                                        Y, out);
  // epilogue: out = 0.25*(e0 + X)
  const int n4 = NNODES * EMB / 4;
  final_combine<<<(n4 + 255) / 256, blk, 0, stream>>>(user_emb, item_emb, out);
}

// Round 2
// 3312.403 us; speedup vs baseline: 2.0430x; 2.0430x over previous
//
#include <hip/hip_runtime.h>

// LightGCN: out = 0.25*(e0 + S e0 + S^2 e0 + S^3 e0), S = 10M-nnz COO over 500k nodes.
// R2 strategy: counting-sort COO -> CSR once per launch, then 3 atomic-free CSR
// SpMM layers (one wave per row, register acc). Horner with streamed Z=e0+X keeps
// one gather per nz per layer.
//   Z = e0; X = S Z; Z = e0+X; X = S Z; Z = e0+X; X = S Z; out = 0.25*(e0 + X)
//   (X = d_out, Z in ws). X1=e1, Z2=e0+e1, X2=e1+e2, Z3=e0+e1+e2, X3=e1+e2+e3. Correct.

#define NUSERS 100000
#define NNODES 500000
#define EMB 64

#define SCAN_BLOCK 256
#define SCAN_CHUNK 1024  // 4 elements per thread

// ---------------- preprocessing ----------------

__global__ void hist_kernel(const int* __restrict__ rows, int nnz,
                            int* __restrict__ counts) {
  int i = blockIdx.x * blockDim.x + threadIdx.x;
  int stride = gridDim.x * blockDim.x;
  for (; i < nnz; i += stride) atomicAdd(&counts[rows[i]], 1);
}

// Per-block exclusive scan of `counts` into `excl`, block totals into bsums.
__global__ void scan1_kernel(const int* __restrict__ counts, int n,
                             int* __restrict__ excl, int* __restrict__ bsums) {
  __shared__ int s[SCAN_BLOCK];
  const int t = threadIdx.x;
  const int base = blockIdx.x * SCAN_CHUNK + t * 4;
  int e[4];
  int tsum = 0;
#pragma unroll
  for (int j = 0; j < 4; ++j) {
    e[j] = (base + j < n) ? counts[base + j] : 0;
    tsum += e[j];
  }
  s[t] = tsum;
  __syncthreads();
  for (int off = 1; off < SCAN_BLOCK; off <<= 1) {
    int v = (t >= off) ? s[t - off] : 0;
    __syncthreads();
    s[t] += v;
    __syncthreads();
  }
  int run = s[t] - tsum;  // exclusive offset of this thread within block
  if (t == SCAN_BLOCK - 1) bsums[blockIdx.x] = s[t];
#pragma unroll
  for (int j = 0; j < 4; ++j) {
    if (base + j < n) excl[base + j] = run;
    run += e[j];
  }
}

// Single-block exclusive scan of block sums (nb <= 1024), in place.
__global__ void scan2_kernel(int* __restrict__ bsums, int nb) {
  __shared__ int s[SCAN_BLOCK];
  const int t = threadIdx.x;
  const int base = t * 4;
  int e[4];
  int tsum = 0;
#pragma unroll
  for (int j = 0; j < 4; ++j) {
    e[j] = (base + j < nb) ? bsums[base + j] : 0;
    tsum += e[j];
  }
  s[t] = tsum;
  __syncthreads();
  for (int off = 1; off < SCAN_BLOCK; off <<= 1) {
    int v = (t >= off) ? s[t - off] : 0;
    __syncthreads();
    s[t] += v;
    __syncthreads();
  }
  int run = s[t] - tsum;
#pragma unroll
  for (int j = 0; j < 4; ++j) {
    if (base + j < nb) bsums[base + j] = run;
    run += e[j];
  }
}

// row_ptr[i] += bsums[i/1024]; cursor[i] = row_ptr[i]; row_ptr[n] = nnz.
__global__ void scan3_kernel(int* __restrict__ row_ptr,
                             const int* __restrict__ bsums, int n, int nnz,
                             int* __restrict__ cursor) {
  int i = blockIdx.x * blockDim.x + threadIdx.x;
  if (i < n) {
    int v = row_ptr[i] + bsums[i / SCAN_CHUNK];
    row_ptr[i] = v;
    cursor[i] = v;
  }
  if (i == 0) row_ptr[n] = nnz;
}

__global__ void scatter_kernel(const int* __restrict__ rows,
                               const int* __restrict__ cols,
                               const float* __restrict__ vals, int nnz,
                               int* __restrict__ cursor,
                               uint2* __restrict__ pairs) {
  int i = blockIdx.x * blockDim.x + threadIdx.x;
  int stride = gridDim.x * blockDim.x;
  for (; i < nnz; i += stride) {
    int r = rows[i];
    int pos = atomicAdd(&cursor[r], 1);
    pairs[pos] = make_uint2((unsigned)cols[i], __float_as_uint(vals[i]));
  }
}

// ---------------- propagation ----------------

// Z = e0 (+ X), float4-vectorized streaming.
__global__ void combine_kernel(const float4* __restrict__ user4,
                               const float4* __restrict__ item4,
                               const float4* __restrict__ X4,
                               float4* __restrict__ Z4, int hasX) {
  const int n4 = NNODES * EMB / 4;
  const int u4 = NUSERS * EMB / 4;
  int i = blockIdx.x * blockDim.x + threadIdx.x;
  if (i >= n4) return;
  float4 a = (i < u4) ? user4[i] : item4[i - u4];
  if (hasX) {
    float4 b = X4[i];
    a.x += b.x; a.y += b.y; a.z += b.z; a.w += b.w;
  }
  Z4[i] = a;
}

// One wave per row: X[r,:] = sum_i val_i * Z[col_i,:]. No atomics.
__global__ void spmm_csr(const int* __restrict__ row_ptr,
                         const uint2* __restrict__ pairs,
                         const float* __restrict__ Z, float* __restrict__ X) {
  const int lane = threadIdx.x & 63;
  const int wave = (int)((blockIdx.x * blockDim.x + threadIdx.x) >> 6);
  if (wave >= NNODES) return;
  const int start = row_ptr[wave];
  const int end = row_ptr[wave + 1];
  float acc = 0.f;
  int i = start;
  for (; i + 1 < end; i += 2) {  // 2-way unroll for memory-level parallelism
    uint2 p0 = pairs[i];
    uint2 p1 = pairs[i + 1];
    float x0 = Z[(size_t)p0.x * EMB + lane];
    float x1 = Z[(size_t)p1.x * EMB + lane];
    acc += __uint_as_float(p0.y) * x0;
    acc += __uint_as_float(p1.y) * x1;
  }
  if (i < end) {
    uint2 p = pairs[i];
    acc += __uint_as_float(p.y) * Z[(size_t)p.x * EMB + lane];
  }
  X[(size_t)wave * EMB + lane] = acc;
}

// out = 0.25*(e0 + out) in place.
__global__ void finalize_kernel(const float4* __restrict__ user4,
                                const float4* __restrict__ item4,
                                float4* __restrict__ X4) {
  const int n4 = NNODES * EMB / 4;
  const int u4 = NUSERS * EMB / 4;
  int i = blockIdx.x * blockDim.x + threadIdx.x;
  if (i >= n4) return;
  float4 a = (i < u4) ? user4[i] : item4[i - u4];
  float4 b = X4[i];
  b.x = 0.25f * (a.x + b.x);
  b.y = 0.25f * (a.y + b.y);
  b.z = 0.25f * (a.z + b.z);
  b.w = 0.25f * (a.w + b.w);
  X4[i] = b;
}

// ---------------- fallback (R1 atomic path, used only if ws too small) ----------------

__global__ void spmm_atomic(const float* __restrict__ vals,
                            const int* __restrict__ rows,
                            const int* __restrict__ cols,
                            const float* __restrict__ user_emb,
                            const float* __restrict__ item_emb,
                            const float* __restrict__ prev, int nnz,
                            float* __restrict__ y) {
  const int lane = threadIdx.x & 63;
  int wave = (int)((blockIdx.x * blockDim.x + threadIdx.x) >> 6);
  const int nwaves = (int)((gridDim.x * blockDim.x) >> 6);
  for (int nz = wave; nz < nnz; nz += nwaves) {
    float v = vals[nz];
    int r = rows[nz];
    int c = cols[nz];
    float xv = (c < NUSERS) ? user_emb[(size_t)c * EMB + lane]
                            : item_emb[(size_t)(c - NUSERS) * EMB + lane];
    if (prev) xv += prev[(size_t)c * EMB + lane];
    atomicAdd(&y[(size_t)r * EMB + lane], v * xv);
  }
}

// ---------------- launch ----------------

extern "C" void kernel_launch(void* const* d_in, const int* in_sizes, int n_in,
                              void* d_out, int out_size, void* d_ws, size_t ws_size,
                              hipStream_t stream) {
  const float* user_emb = (const float*)d_in[0];
  const float* item_emb = (const float*)d_in[1];
  const float* vals     = (const float*)d_in[2];
  const int*   rows     = (const int*)d_in[3];
  const int*   cols     = (const int*)d_in[4];
  const int nnz = in_sizes[2];
  float* X = (float*)d_out;  // 128 MB, doubles as ping-pong buffer

  const size_t embBytes = (size_t)NNODES * EMB * sizeof(float);   // 128 MB
  const size_t pairBytes = (size_t)nnz * sizeof(uint2);           // 80 MB
  const size_t ptrBytes = ((size_t)(NNODES + 1) * 4 + 255) & ~(size_t)255;
  const size_t curBytes = ((size_t)NNODES * 4 + 255) & ~(size_t)255;
  const int nblocks1 = (NNODES + SCAN_CHUNK - 1) / SCAN_CHUNK;    // 489
  const size_t bsumBytes = ((size_t)nblocks1 * 4 + 255) & ~(size_t)255;
  const size_t need = embBytes + pairBytes + ptrBytes + curBytes + bsumBytes;

  dim3 blk(256);

  if (ws_size < need) {
    // Fallback: R1 atomic path (needs only 128 MB of ws).
    float* Y = (float*)d_ws;
    hipMemsetAsync(X, 0, embBytes, stream);
    hipMemsetAsync(Y, 0, embBytes, stream);
    dim3 grid(4096);
    spmm_atomic<<<grid, blk, 0, stream>>>(vals, rows, cols, user_emb, item_emb, nullptr, nnz, X);
    spmm_atomic<<<grid, blk, 0, stream>>>(vals, rows, cols, user_emb, item_emb, X, nnz, Y);
    hipMemsetAsync(X, 0, embBytes, stream);
    spmm_atomic<<<grid, blk, 0, stream>>>(vals, rows, cols, user_emb, item_emb, Y, nnz, X);
    const int n4 = NNODES * EMB / 4;
    finalize_kernel<<<(n4 + 255) / 256, blk, 0, stream>>>(
        (const float4*)user_emb, (const float4*)item_emb, (float4*)X);
    return;
  }

  char* ws = (char*)d_ws;
  float* Z      = (float*)ws;                 ws += embBytes;
  uint2* pairs  = (uint2*)ws;                 ws += pairBytes;
  int*   rowp   = (int*)ws;                   ws += ptrBytes;
  int*   cursor = (int*)ws;                   ws += curBytes;
  int*   bsums  = (int*)ws;

  // --- build CSR ---
  hipMemsetAsync(cursor, 0, (size_t)NNODES * 4, stream);  // cursor doubles as counts
  hist_kernel<<<2048, blk, 0, stream>>>(rows, nnz, cursor);
  scan1_kernel<<<nblocks1, SCAN_BLOCK, 0, stream>>>(cursor, NNODES, rowp, bsums);
  scan2_kernel<<<1, SCAN_BLOCK, 0, stream>>>(bsums, nblocks1);
  scan3_kernel<<<(NNODES + 255) / 256, blk, 0, stream>>>(rowp, bsums, NNODES, nnz, cursor);
  scatter_kernel<<<2048, blk, 0, stream>>>(rows, cols, vals, nnz, cursor, pairs);

  // --- 3 propagation layers, Horner form ---
  const int n4 = NNODES * EMB / 4;
  const int cgrid = (n4 + 255) / 256;
  const int sgrid = (NNODES * 64) / 256;  // one wave per row, 4 waves/block

  combine_kernel<<<cgrid, blk, 0, stream>>>((const float4*)user_emb, (const float4*)item_emb,
                                            nullptr, (float4*)Z, 0);
  spmm_csr<<<sgrid, blk, 0, stream>>>(rowp, pairs, Z, X);
  combine_kernel<<<cgrid, blk, 0, stream>>>((const float4*)user_emb, (const float4*)item_emb,
                                            (const float4*)X, (float4*)Z, 1);
  spmm_csr<<<sgrid, blk, 0, stream>>>(rowp, pairs, Z, X);
  combine_kernel<<<cgrid, blk, 0, stream>>>((const float4*)user_emb, (const float4*)item_emb,
                                            (const float4*)X, (float4*)Z, 1);
  spmm_csr<<<sgrid, blk, 0, stream>>>(rowp, pairs, Z, X);

  finalize_kernel<<<cgrid, blk, 0, stream>>>((const float4*)user_emb, (const float4*)item_emb,
                                             (float4*)X);
}